// Round 3
// baseline (348.343 us; speedup 1.0000x reference)
//
#include <hip/hip_runtime.h>

#define PI_F 3.14159265358979323846f

// ---------------------------------------------------------------------------
// Kernel 1: build the 32x64 combined operator C = B[:, :26] @ A[:26, :]
//   A = M64^3, B = (M32^T)^3 (the reference's matmul chain hits only the H
//   axis, three times each way). fp32 with exact integer mod-2pi reduction
//   of the cos arguments; C error ~1e-6, invisible vs the 0.1 threshold.
// Single block, 256 threads.
// ---------------------------------------------------------------------------
__global__ __launch_bounds__(256) void build_C_kernel(float* __restrict__ Cout) {
    __shared__ float sM[64 * 64];    // M64
    __shared__ float sQ[64 * 64];    // M64^2
    __shared__ float sA[64 * 64];    // M64^3
    __shared__ float s32a[32 * 32];  // M32
    __shared__ float s32b[32 * 32];  // M32^2
    __shared__ float s32c[32 * 32];  // M32^3
    const int t = threadIdx.x;

    for (int i = t; i < 4096; i += 256) {
        int k = i >> 6, n = i & 63;
        int m = ((2 * n + 1) * k) & 255;               // cos(pi*m/128): period 256
        float v = (k == 0) ? 0.125f                     // 1/sqrt(64)
                           : 0.17677669529663688f       // sqrt(2/64)
                             * cosf(PI_F * (float)m / 128.0f);
        sM[i] = v;
    }
    for (int i = t; i < 1024; i += 256) {
        int k = i >> 5, n = i & 31;
        int m = ((2 * n + 1) * k) & 127;               // cos(pi*m/64): period 128
        float v = (k == 0) ? 0.17677669529663688f       // 1/sqrt(32)
                           : 0.25f                      // sqrt(2/32)
                             * cosf(PI_F * (float)m / 64.0f);
        s32a[i] = v;
    }
    __syncthreads();

    for (int i = t; i < 4096; i += 256) {
        int r = i >> 6, c = i & 63;
        float acc = 0.f;
        for (int k = 0; k < 64; ++k) acc = fmaf(sM[r * 64 + k], sM[k * 64 + c], acc);
        sQ[i] = acc;
    }
    for (int i = t; i < 1024; i += 256) {
        int r = i >> 5, c = i & 31;
        float acc = 0.f;
        for (int k = 0; k < 32; ++k) acc = fmaf(s32a[r * 32 + k], s32a[k * 32 + c], acc);
        s32b[i] = acc;
    }
    __syncthreads();

    for (int i = t; i < 4096; i += 256) {
        int r = i >> 6, c = i & 63;
        float acc = 0.f;
        for (int k = 0; k < 64; ++k) acc = fmaf(sQ[r * 64 + k], sM[k * 64 + c], acc);
        sA[i] = acc;
    }
    for (int i = t; i < 1024; i += 256) {
        int r = i >> 5, c = i & 31;
        float acc = 0.f;
        for (int k = 0; k < 32; ++k) acc = fmaf(s32b[r * 32 + k], s32a[k * 32 + c], acc);
        s32c[i] = acc;
    }
    __syncthreads();

    // C[h][k] = sum_{h1<26} M32^3[h1][h] * A[h1][k]
    for (int i = t; i < 2048; i += 256) {
        int h = i >> 6, k = i & 63;
        float acc = 0.f;
        for (int h1 = 0; h1 < 26; ++h1)
            acc = fmaf(s32c[h1 * 32 + h], sA[h1 * 64 + k], acc);
        Cout[i] = acc;
    }
}

// ---------------------------------------------------------------------------
// Kernel 2: out[bc,d,h,w] = (d<26 && w<26) ? sum_k C[h,k] * x[bc,d,k,w] : 0
// One wave per (bc,d) slice; block = 4 slices. Lane l: wq=l&7, hb=l>>3,
// h in {hb, hb+8, hb+16, hb+24}.
// v3: NO x LDS staging — for fixed k the whole wave's x quads live in ONE
// 128 B cache line (8 distinct 16 B addrs x 8-lane broadcast), so a direct
// global float4 load is already a single coalesced transaction. LDS holds
// only C (stride 68: rows 16 B-aligned for ds_read_b128; 68%32==4 tiles all
// banks across the 8 hb groups). LDS/block 41.5 -> 8.7 KB.
// ---------------------------------------------------------------------------
#define FMA4(a, c, xv)                    \
    a.x = fmaf(c, xv.x, a.x);             \
    a.y = fmaf(c, xv.y, a.y);             \
    a.z = fmaf(c, xv.z, a.z);             \
    a.w = fmaf(c, xv.w, a.w)

__global__ __launch_bounds__(256) void spectral_pool_kernel(
    const float* __restrict__ x, const float* __restrict__ C,
    float* __restrict__ out) {
    __shared__ __align__(16) float sC[32 * 68];

    const int t   = threadIdx.x;
    const int blk = blockIdx.x;
    const int bc  = blk >> 3;   // 0..255 (b*32 + c)
    const int dg  = blk & 7;    // d-group of 4
    const int s   = t >> 6;     // wave id = slice
    const int l   = t & 63;
    const int wq  = l & 7;      // w-quad
    const int hb  = l >> 3;     // h base 0..7
    const int d   = dg * 4 + s;

    if (dg != 7) {  // dg==7 blocks are pure zero-fill, never read sC
        for (int i = t; i < 2048; i += 256) sC[(i >> 6) * 68 + (i & 63)] = C[i];
        __syncthreads();
    }

    float* op = out + (size_t)(bc * 32 + d) * 1024;

    if (d >= 26) {
        const float4 z = make_float4(0.f, 0.f, 0.f, 0.f);
#pragma unroll
        for (int j = 0; j < 4; ++j)
            *(float4*)(op + (j * 64 + l) * 4) = z;
        return;
    }

    const float* xp = x + (size_t)(bc * 64 + d) * 4096 + wq * 4;
    const float* cp = sC + hb * 68;

    float4 a0 = make_float4(0.f, 0.f, 0.f, 0.f);
    float4 a1 = a0, a2 = a0, a3 = a0;

#pragma unroll
    for (int k4 = 0; k4 < 64; k4 += 4) {
        const float4 x0 = *(const float4*)(xp + (k4 + 0) * 64);
        const float4 x1 = *(const float4*)(xp + (k4 + 1) * 64);
        const float4 x2 = *(const float4*)(xp + (k4 + 2) * 64);
        const float4 x3 = *(const float4*)(xp + (k4 + 3) * 64);
        const float4 c0 = *(const float4*)(cp + k4);
        const float4 c1 = *(const float4*)(cp + 8 * 68 + k4);
        const float4 c2 = *(const float4*)(cp + 16 * 68 + k4);
        const float4 c3 = *(const float4*)(cp + 24 * 68 + k4);

        FMA4(a0, c0.x, x0); FMA4(a0, c0.y, x1); FMA4(a0, c0.z, x2); FMA4(a0, c0.w, x3);
        FMA4(a1, c1.x, x0); FMA4(a1, c1.y, x1); FMA4(a1, c1.z, x2); FMA4(a1, c1.w, x3);
        FMA4(a2, c2.x, x0); FMA4(a2, c2.y, x1); FMA4(a2, c2.z, x2); FMA4(a2, c2.w, x3);
        FMA4(a3, c3.x, x0); FMA4(a3, c3.y, x1); FMA4(a3, c3.z, x2); FMA4(a3, c3.w, x3);
    }

    // mask w >= 26 (wq==6: zero .z/.w for w=26,27; wq==7 fully zero)
    const int w0 = wq * 4;
    if (w0 >= 26) {
        a0 = a1 = a2 = a3 = make_float4(0.f, 0.f, 0.f, 0.f);
    } else if (w0 == 24) {
        a0.z = a0.w = 0.f; a1.z = a1.w = 0.f;
        a2.z = a2.w = 0.f; a3.z = a3.w = 0.f;
    }

    *(float4*)(op + hb * 32 + w0)        = a0;
    *(float4*)(op + (hb + 8) * 32 + w0)  = a1;
    *(float4*)(op + (hb + 16) * 32 + w0) = a2;
    *(float4*)(op + (hb + 24) * 32 + w0) = a3;
}

extern "C" void kernel_launch(void* const* d_in, const int* in_sizes, int n_in,
                              void* d_out, int out_size, void* d_ws, size_t ws_size,
                              hipStream_t stream) {
    const float* x = (const float*)d_in[0];
    float* out = (float*)d_out;
    float* C = (float*)d_ws;  // 32*64 fp32 = 8 KB scratch

    hipLaunchKernelGGL(build_C_kernel, dim3(1), dim3(256), 0, stream, C);
    hipLaunchKernelGGL(spectral_pool_kernel, dim3(2048), dim3(256), 0, stream,
                       x, C, out);
}

// Round 4
// 324.428 us; speedup vs baseline: 1.0737x; 1.0737x over previous
//
#include <hip/hip_runtime.h>

#define PI_F 3.14159265358979323846f

// ---------------------------------------------------------------------------
// Kernel 1: build the 32x64 combined operator C = B[:, :26] @ A[:26, :]
//   A = M64^3, B = (M32^T)^3 (the reference's matmul chain hits only the H
//   axis, three times each way). fp32 with exact integer mod-2pi reduction
//   of the cos arguments; C error ~1e-6, invisible vs the 0.1 threshold.
// Single block, 1024 threads (one CU, ~0.8 us).
// ---------------------------------------------------------------------------
__global__ __launch_bounds__(1024) void build_C_kernel(float* __restrict__ Cout) {
    __shared__ float sM[64 * 64];    // M64
    __shared__ float sQ[64 * 64];    // M64^2
    __shared__ float sA[64 * 64];    // M64^3
    __shared__ float s32a[32 * 32];  // M32
    __shared__ float s32b[32 * 32];  // M32^2
    __shared__ float s32c[32 * 32];  // M32^3
    const int t = threadIdx.x;

    for (int i = t; i < 4096; i += 1024) {
        int k = i >> 6, n = i & 63;
        int m = ((2 * n + 1) * k) & 255;               // cos(pi*m/128): period 256
        float v = (k == 0) ? 0.125f                     // 1/sqrt(64)
                           : 0.17677669529663688f       // sqrt(2/64)
                             * cosf(PI_F * (float)m / 128.0f);
        sM[i] = v;
    }
    if (t < 1024) {
        int k = t >> 5, n = t & 31;
        int m = ((2 * n + 1) * k) & 127;               // cos(pi*m/64): period 128
        float v = (k == 0) ? 0.17677669529663688f       // 1/sqrt(32)
                           : 0.25f                      // sqrt(2/32)
                             * cosf(PI_F * (float)m / 64.0f);
        s32a[t] = v;
    }
    __syncthreads();

    for (int i = t; i < 4096; i += 1024) {
        int r = i >> 6, c = i & 63;
        float acc = 0.f;
        for (int k = 0; k < 64; ++k) acc = fmaf(sM[r * 64 + k], sM[k * 64 + c], acc);
        sQ[i] = acc;
    }
    if (t < 1024) {
        int r = t >> 5, c = t & 31;
        float acc = 0.f;
        for (int k = 0; k < 32; ++k) acc = fmaf(s32a[r * 32 + k], s32a[k * 32 + c], acc);
        s32b[t] = acc;
    }
    __syncthreads();

    for (int i = t; i < 4096; i += 1024) {
        int r = i >> 6, c = i & 63;
        float acc = 0.f;
        for (int k = 0; k < 64; ++k) acc = fmaf(sQ[r * 64 + k], sM[k * 64 + c], acc);
        sA[i] = acc;
    }
    if (t < 1024) {
        int r = t >> 5, c = t & 31;
        float acc = 0.f;
        for (int k = 0; k < 32; ++k) acc = fmaf(s32b[r * 32 + k], s32a[k * 32 + c], acc);
        s32c[t] = acc;
    }
    __syncthreads();

    // C[h][k] = sum_{h1<26} M32^3[h1][h] * A[h1][k]
    for (int i = t; i < 2048; i += 1024) {
        int h = i >> 6, k = i & 63;
        float acc = 0.f;
        for (int h1 = 0; h1 < 26; ++h1)
            acc = fmaf(s32c[h1 * 32 + h], sA[h1 * 64 + k], acc);
        Cout[i] = acc;
    }
}

// ---------------------------------------------------------------------------
// Kernel 2 (round-2 structure, best measured: 336.6 us total):
//   out[bc,d,h,w] = (d<26 && w<26) ? sum_k C[h,k] * x[bc,d,k,w] : 0
// One wave per (bc,d) slice; block = 4 slices. Lane l: wq=l&7, hb=l>>3,
// h in {hb, hb+8, hb+16, hb+24}. x tile (64x32 fp32 = 8 KB/slice) staged via
// global_load_lds width 16 (R3 showed direct per-k global loads are ~12 us
// slower — latency re-enters the inner loop). sC stride 68: rows 16 B-aligned
// for ds_read_b128; 68%32==4 tiles all 32 banks across the 8 hb groups.
// Inner loop per 4 k's: 8 ds_read_b128 + 64 fma.
// ---------------------------------------------------------------------------
#define FMA4(a, c, xv)                    \
    a.x = fmaf(c, xv.x, a.x);             \
    a.y = fmaf(c, xv.y, a.y);             \
    a.z = fmaf(c, xv.z, a.z);             \
    a.w = fmaf(c, xv.w, a.w)

__global__ __launch_bounds__(256) void spectral_pool_kernel(
    const float* __restrict__ x, const float* __restrict__ C,
    float* __restrict__ out) {
    __shared__ __align__(16) float sC[32 * 68];
    __shared__ __align__(16) float xs[4][64 * 32];

    const int t   = threadIdx.x;
    const int blk = blockIdx.x;
    const int bc  = blk >> 3;   // 0..255 (b*32 + c)
    const int dg  = blk & 7;    // d-group of 4
    const int s   = t >> 6;     // wave id = slice
    const int l   = t & 63;
    const int wq  = l & 7;      // w-quad
    const int hb  = l >> 3;     // h base 0..7
    const int d   = dg * 4 + s;

    const bool active = (d < 26);
    if (active) {
        const float* xp = x + (size_t)(bc * 64 + d) * 4096;
#pragma unroll
        for (int it = 0; it < 8; ++it) {
            int idx = it * 64 + l;            // float4 index in 64x32 tile
            int row = idx >> 3, q = idx & 7;  // row<64, first 8 quads of W=64
            const float* g = xp + row * 64 + q * 4;
            __builtin_amdgcn_global_load_lds(
                (const __attribute__((address_space(1))) void*)g,
                (__attribute__((address_space(3))) void*)(&xs[s][it * 256]),
                16, 0, 0);
        }
    }

    if (dg != 7) {  // dg==7 blocks are pure zero-fill, never read sC
        // vectorized C stage: thread t covers C[8t..8t+7] -> row t>>3, col (t&7)*8
        {
            const float4* cg = (const float4*)(C + t * 8);
            float4 g0 = cg[0], g1 = cg[1];
            float* dst = sC + (t >> 3) * 68 + (t & 7) * 8;
            *(float4*)(dst)     = g0;
            *(float4*)(dst + 4) = g1;
        }
        __syncthreads();
    }

    float* op = out + (size_t)(bc * 32 + d) * 1024;

    if (!active) {
        const float4 z = make_float4(0.f, 0.f, 0.f, 0.f);
#pragma unroll
        for (int j = 0; j < 4; ++j)
            *(float4*)(op + (j * 64 + l) * 4) = z;
        return;
    }

    const float* xss = xs[s] + wq * 4;
    const float* cp  = sC + hb * 68;

    float4 a0 = make_float4(0.f, 0.f, 0.f, 0.f);
    float4 a1 = a0, a2 = a0, a3 = a0;

#pragma unroll 4
    for (int k4 = 0; k4 < 64; k4 += 4) {
        const float4 c0 = *(const float4*)(cp + k4);
        const float4 c1 = *(const float4*)(cp + 8 * 68 + k4);
        const float4 c2 = *(const float4*)(cp + 16 * 68 + k4);
        const float4 c3 = *(const float4*)(cp + 24 * 68 + k4);
        const float4 x0 = *(const float4*)(xss + (k4 + 0) * 32);
        const float4 x1 = *(const float4*)(xss + (k4 + 1) * 32);
        const float4 x2 = *(const float4*)(xss + (k4 + 2) * 32);
        const float4 x3 = *(const float4*)(xss + (k4 + 3) * 32);

        FMA4(a0, c0.x, x0); FMA4(a0, c0.y, x1); FMA4(a0, c0.z, x2); FMA4(a0, c0.w, x3);
        FMA4(a1, c1.x, x0); FMA4(a1, c1.y, x1); FMA4(a1, c1.z, x2); FMA4(a1, c1.w, x3);
        FMA4(a2, c2.x, x0); FMA4(a2, c2.y, x1); FMA4(a2, c2.z, x2); FMA4(a2, c2.w, x3);
        FMA4(a3, c3.x, x0); FMA4(a3, c3.y, x1); FMA4(a3, c3.z, x2); FMA4(a3, c3.w, x3);
    }

    // mask w >= 26 (wq==6: zero .z/.w for w=26,27; wq==7 fully zero)
    const int w0 = wq * 4;
    if (w0 >= 26) {
        a0 = a1 = a2 = a3 = make_float4(0.f, 0.f, 0.f, 0.f);
    } else if (w0 == 24) {
        a0.z = a0.w = 0.f; a1.z = a1.w = 0.f;
        a2.z = a2.w = 0.f; a3.z = a3.w = 0.f;
    }

    *(float4*)(op + hb * 32 + w0)        = a0;
    *(float4*)(op + (hb + 8) * 32 + w0)  = a1;
    *(float4*)(op + (hb + 16) * 32 + w0) = a2;
    *(float4*)(op + (hb + 24) * 32 + w0) = a3;
}

extern "C" void kernel_launch(void* const* d_in, const int* in_sizes, int n_in,
                              void* d_out, int out_size, void* d_ws, size_t ws_size,
                              hipStream_t stream) {
    const float* x = (const float*)d_in[0];
    float* out = (float*)d_out;
    float* C = (float*)d_ws;  // 32*64 fp32 = 8 KB scratch

    hipLaunchKernelGGL(build_C_kernel, dim3(1), dim3(1024), 0, stream, C);
    hipLaunchKernelGGL(spectral_pool_kernel, dim3(2048), dim3(256), 0, stream,
                       x, C, out);
}